// Round 1
// 460.161 us; speedup vs baseline: 1.4248x; 1.4248x over previous
//
#include <hip/hip_runtime.h>

// New_msa fused implementation for MI355X (gfx950) — polish round 1.
// vs prev (656 µs): k_final 3 blocks/CU + XOR-swizzled LDS + rcp-GELU + native
// bf16 cvt + XCD tile remap; k_vgram Gram frags from swizzled transposed LDS
// (kills 1024 strided scalar global loads/thread); k_attn S staged in LDS;
// k_reduce 4x occupancy via atomics.
//
// ws layout (bytes):            size
//   v bf16   [4][65536][128]    67,108,864   @ 0
//   partialS [512][128][128]f32 33,554,432   @ 67,108,864
//   S        [4][128][128] f32     262,144   @ 100,663,296
//   W2T bf16 [4][128][128]         131,072   @ 100,925,440
//   pw bf16  [128][512]            131,072   @ 101,056,512

using bf16x8 = __attribute__((ext_vector_type(8))) short;
using f32x4  = __attribute__((ext_vector_type(4))) float;

__device__ __forceinline__ unsigned short f2bf(float f) {
  __bf16 h = (__bf16)f;                       // RNE, compiler pairs into v_cvt_pk_bf16_f32
  return __builtin_bit_cast(unsigned short, h);
}
__device__ __forceinline__ float bf2f(unsigned short u) {
  union { unsigned u; float f; } v; v.u = ((unsigned)u) << 16;
  return v.f;
}
__device__ __forceinline__ float gelu_f(float x) {
  // tanh-form GELU, rcp instead of fp32 divide (|err| ~3e-3 vs erf form)
  float u = 0.7978845608028654f * (x + 0.044715f * x * x * x);
  float e = __expf(2.0f * u);
  float th = 1.0f - 2.0f * __builtin_amdgcn_rcpf(e + 1.0f);  // inf-safe
  return 0.5f * x * (1.0f + th);
}

// ---------------- K0: pw_w fp32 -> bf16, and zero S for atomic reduce -------
__global__ void k_prep(const float* __restrict__ pw, unsigned short* __restrict__ pwb,
                       float* __restrict__ S) {
  int blk = blockIdx.x;
  if (blk < 256) { int idx = blk * 256 + threadIdx.x; pwb[idx] = f2bf(pw[idx]); }
  else           { int idx = (blk - 256) * 256 + threadIdx.x; S[idx] = 0.f; }
}

// ---------------- K1: fused v = x@Wv  and  partial S = x^T x ----------------
// grid 512 (= 4 batches * 128 chunks of 512 rows), 256 threads.
// LDS: WvT 32K + xs 16K + xsT 16K = 64K (2 blocks/CU; grid-limited anyway).
__global__ __launch_bounds__(256, 2) void k_vgram(
    const float* __restrict__ x, const float* __restrict__ Wv,
    unsigned short* __restrict__ vout, float* __restrict__ partial) {
  __shared__ unsigned short WvT[128 * 128];   // [c_out][c_in], 256B rows, swizzled
  __shared__ unsigned short xs [64 * 128];    // [row][c_in],   256B rows, swizzled
  __shared__ unsigned short xsT[128 * 64];    // [c_in][row],   128B rows, swizzled
  char* WvT_c = (char*)WvT; char* xs_c = (char*)xs; char* xsT_c = (char*)xsT;
  const int tid = threadIdx.x;
  const int bid = blockIdx.x;
  const int b = bid >> 7;
  const long n0 = (long)(bid & 127) * 512;
  const float* __restrict__ xb = x + (long)b * 65536 * 128;

  { // stage Wv transposed -> bf16 (one-time per block; Wv is L2-hot)
    int c = tid >> 1;
    int o0 = (tid & 1) * 64;
    const float* src = Wv + c * 128 + o0;
    #pragma unroll
    for (int u = 0; u < 64; u += 4) {
      float4 w = *(const float4*)(src + u);
      unsigned short q0 = f2bf(w.x), q1 = f2bf(w.y), q2 = f2bf(w.z), q3 = f2bf(w.w);
      int o = o0 + u;
      *(unsigned short*)(WvT_c + (o + 0) * 256 + ((2 * c) ^ (((o + 0) & 7) << 4))) = q0;
      *(unsigned short*)(WvT_c + (o + 1) * 256 + ((2 * c) ^ (((o + 1) & 7) << 4))) = q1;
      *(unsigned short*)(WvT_c + (o + 2) * 256 + ((2 * c) ^ (((o + 2) & 7) << 4))) = q2;
      *(unsigned short*)(WvT_c + (o + 3) * 256 + ((2 * c) ^ (((o + 3) & 7) << 4))) = q3;
    }
  }
  __syncthreads();

  const int wave = tid >> 6, lane = tid & 63;
  const int quad = lane >> 4, l16 = lane & 15;
  const int swl = (l16 & 7) << 4;

  f32x4 accg[2][8];   // Gram accumulators: m-tiles {2w,2w+1} x 8 n-tiles
  #pragma unroll
  for (int i = 0; i < 2; ++i)
    #pragma unroll
    for (int nt = 0; nt < 8; ++nt) accg[i][nt] = (f32x4){0.f, 0.f, 0.f, 0.f};

  for (int so = 0; so < 8; ++so) {
    const long r0 = n0 + so * 64;
    { // stage 64 rows of x -> bf16 LDS, both row-major (xs) and transposed (xsT)
      int row = tid >> 2;
      int c0 = (tid & 3) * 32;
      const float* src = xb + (r0 + row) * 128 + c0;
      char* xrow = xs_c + row * 256;
      const int sw = (row & 7) << 4;
      #pragma unroll
      for (int u = 0; u < 32; u += 4) {
        float4 t = *(const float4*)(src + u);
        ushort4 p;
        p.x = f2bf(t.x); p.y = f2bf(t.y); p.z = f2bf(t.z); p.w = f2bf(t.w);
        int c = c0 + u;
        *(ushort4*)(xrow + ((2 * c) ^ sw)) = p;
        *(unsigned short*)(xsT_c + (c + 0) * 128 + ((2 * row) ^ (((c + 0) & 7) << 4))) = p.x;
        *(unsigned short*)(xsT_c + (c + 1) * 128 + ((2 * row) ^ (((c + 1) & 7) << 4))) = p.y;
        *(unsigned short*)(xsT_c + (c + 2) * 128 + ((2 * row) ^ (((c + 2) & 7) << 4))) = p.z;
        *(unsigned short*)(xsT_c + (c + 3) * 128 + ((2 * row) ^ (((c + 3) & 7) << 4))) = p.w;
      }
    }
    __syncthreads();

    // ---- v-GEMM: D[row, c_out] = x-tile @ Wv ----
    f32x4 accv[8];
    #pragma unroll
    for (int nt = 0; nt < 8; ++nt) accv[nt] = (f32x4){0.f, 0.f, 0.f, 0.f};
    #pragma unroll
    for (int ks = 0; ks < 4; ++ks) {
      bf16x8 af = *(const bf16x8*)(xs_c + (16 * wave + l16) * 256 +
                                   ((64 * ks + 16 * quad) ^ swl));
      #pragma unroll
      for (int nt = 0; nt < 8; ++nt) {
        bf16x8 bfr = *(const bf16x8*)(WvT_c + (16 * nt + l16) * 256 +
                                      ((64 * ks + 16 * quad) ^ swl));
        accv[nt] = __builtin_amdgcn_mfma_f32_16x16x32_bf16(af, bfr, accv[nt], 0, 0, 0);
      }
    }
    { // store v (bf16). C/D layout: row = 4*quad+r, col = l16  [m89]
      long rbase = (long)b * 65536 + r0 + 16 * wave + 4 * quad;
      #pragma unroll
      for (int nt = 0; nt < 8; ++nt)
        #pragma unroll
        for (int r = 0; r < 4; ++r)
          vout[(rbase + r) * 128 + 16 * nt + l16] = f2bf(accv[nt][r]);
    }

    // ---- Gram: S += x_tile^T x_tile, frags from swizzled xsT (b128 reads) ----
    #pragma unroll
    for (int ks = 0; ks < 2; ++ks) {
      bf16x8 fr[8];
      bf16x8 fa0, fa1;
      #pragma unroll
      for (int t8 = 0; t8 < 8; ++t8) {
        int cc = 16 * t8 + l16;
        bf16x8 f = *(const bf16x8*)(xsT_c + cc * 128 + ((64 * ks + 16 * quad) ^ swl));
        fr[t8] = f;
        if (t8 == 2 * wave)     fa0 = f;   // avoid dynamic reg-array index
        if (t8 == 2 * wave + 1) fa1 = f;
      }
      #pragma unroll
      for (int nt = 0; nt < 8; ++nt) {
        accg[0][nt] = __builtin_amdgcn_mfma_f32_16x16x32_bf16(fa0, fr[nt], accg[0][nt], 0, 0, 0);
        accg[1][nt] = __builtin_amdgcn_mfma_f32_16x16x32_bf16(fa1, fr[nt], accg[1][nt], 0, 0, 0);
      }
    }
    __syncthreads();
  }

  { // per-block partial S (no atomics; reduced by k_reduce)
    float* pp = partial + (long)bid * 16384;
    #pragma unroll
    for (int i = 0; i < 2; ++i) {
      int mr = 16 * (2 * wave + i) + 4 * quad;
      #pragma unroll
      for (int nt = 0; nt < 8; ++nt)
        #pragma unroll
        for (int r = 0; r < 4; ++r)
          pp[(mr + r) * 128 + 16 * nt + l16] = accg[i][nt][r];
    }
  }
}

// ---------------- K1c: reduce 128 partials per batch -> S (atomic) ----------
// grid 1024: thread sums 32 partials, atomicAdd (4 contenders/address).
__global__ void k_reduce(const float* __restrict__ partial, float* __restrict__ S) {
  int t = blockIdx.x * 256 + threadIdx.x;   // 262144 = 65536 outputs * 4 kg
  int idx = t & 65535;
  int kg  = t >> 16;
  int bb = idx >> 14;
  int ij = idx & 16383;
  const float* p = partial + (long)bb * (128L * 16384) + (long)kg * (32L * 16384) + ij;
  float s = 0.f;
  #pragma unroll 4
  for (int k = 0; k < 32; ++k) s += p[(long)k * 16384];
  atomicAdd(S + idx, s);
}

// ---------------- K2: Gram -> softmax attn -> W2T (per b,h) -----------------
// S staged through LDS fp32 (two 32KB chunks); Tk never materialized.
__global__ __launch_bounds__(256) void k_attn(
    const float* __restrict__ S, const float* __restrict__ Wq,
    const float* __restrict__ Wk, const float* __restrict__ rescale,
    const float* __restrict__ Wproj, unsigned short* __restrict__ W2T) {
  __shared__ float Ssf[64 * 128];   // 32KB: one 64-row chunk of S
  __shared__ float Tq[128][32];
  __shared__ float G[32][33];
  __shared__ float attnS[32][33];
  __shared__ float nq[32];
  __shared__ float nkp[8][32];
  const int tid = threadIdx.x;
  const int b = blockIdx.x >> 2;
  const int h = blockIdx.x & 3;
  const float* Sb = S + b * 16384;
  const int e = tid & 31, ig = tid >> 5, col = 32 * h + e;

  { // Tq = S*Wq_h; nk accumulated inline from the ak side
    float nk_s = 0.f;
    for (int cb = 0; cb < 2; ++cb) {
      __syncthreads();
      #pragma unroll
      for (int u = 0; u < 8; ++u) {       // stage rows [64cb, 64cb+64)
        int idx = u * 1024 + tid * 4;
        *(float4*)&Ssf[idx] = *(const float4*)(Sb + cb * 8192 + idx);
      }
      __syncthreads();
      float aq[8], ak[8];
      #pragma unroll
      for (int m = 0; m < 8; ++m) { aq[m] = 0.f; ak[m] = 0.f; }
      for (int j = 0; j < 128; ++j) {
        float wq = Wq[j * 128 + col];
        float wk = Wk[j * 128 + col];
        #pragma unroll
        for (int m = 0; m < 8; ++m) {     // rows i = 64cb + ig + 8m (stride-8)
          float s = Ssf[(ig + 8 * m) * 128 + j];   // broadcast read (uniform/32)
          aq[m] += s * wq;
          ak[m] += s * wk;
        }
      }
      #pragma unroll
      for (int m = 0; m < 8; ++m) {
        int i = 64 * cb + ig + 8 * m;
        Tq[i][e] = aq[m];
        nk_s += Wk[i * 128 + col] * ak[m];
      }
    }
    nkp[ig][e] = nk_s;
  }
  __syncthreads();
  { // G[d][e] = Wk_d . Tq[:,e]
    int d0 = ig * 4;
    float g[4] = {0.f, 0.f, 0.f, 0.f};
    for (int i = 0; i < 128; ++i) {
      float tq = Tq[i][e];
      #pragma unroll
      for (int d = 0; d < 4; ++d) g[d] += Wk[i * 128 + 32 * h + d0 + d] * tq;
    }
    #pragma unroll
    for (int d = 0; d < 4; ++d) G[d0 + d][e] = g[d];
  }
  if (tid < 32) {          // ||q_e||^2
    float s = 0.f;
    for (int i = 0; i < 128; ++i) s += Wq[i * 128 + col] * Tq[i][tid];
    nq[tid] = s;
  }
  __syncthreads();
  if (tid < 32) {          // softmax over e per row d
    int d = tid;
    float nk_d = 0.f;
    #pragma unroll
    for (int g2 = 0; g2 < 8; ++g2) nk_d += nkp[g2][d];
    float rsc = rescale[h];
    float rk = fmaxf(sqrtf(fmaxf(nk_d, 0.f)), 1e-12f);
    float L[32];
    float mx = -3.4e38f;
    #pragma unroll
    for (int e2 = 0; e2 < 32; ++e2) {
      float rq = fmaxf(sqrtf(fmaxf(nq[e2], 0.f)), 1e-12f);
      float l = G[d][e2] * rsc / (rk * rq);
      L[e2] = l;
      mx = fmaxf(mx, l);
    }
    float sum = 0.f;
    #pragma unroll
    for (int e2 = 0; e2 < 32; ++e2) {
      float p = __expf(L[e2] - mx);
      attnS[d][e2] = p;
      sum += p;
    }
    float inv = 1.0f / sum;
    #pragma unroll
    for (int e2 = 0; e2 < 32; ++e2) attnS[d][e2] *= inv;
  }
  __syncthreads();
  { // W2T[b][co][32h+e] = sum_d attn[d][e] * Wproj[32h+d][co]   (bf16)
    int co = tid & 127;
    int e0 = (tid >> 7) * 16;
    float s[16];
    #pragma unroll
    for (int e2 = 0; e2 < 16; ++e2) s[e2] = 0.f;
    for (int d = 0; d < 32; ++d) {
      float wp = Wproj[(32 * h + d) * 128 + co];
      #pragma unroll
      for (int e2 = 0; e2 < 16; ++e2) s[e2] += attnS[d][e0 + e2] * wp;
    }
    #pragma unroll
    for (int e2 = 0; e2 < 16; ++e2)
      W2T[((long)b * 128 + co) * 128 + 32 * h + e0 + e2] = f2bf(s[e2]);
  }
}

// ---------------- K3: fused gabor + dual GEMM + bias -> out -----------------
// grid 4096 = 4 batches * 32*32 tiles of 8x8 pixels; 256 threads.
// LDS 53.2KB -> 3 blocks/CU; all LDS XOR-swizzled (conflict-free frag reads).
__global__ __launch_bounds__(256, 3) void k_final(
    const unsigned short* __restrict__ v, const unsigned short* __restrict__ W2T,
    const unsigned short* __restrict__ pwb, const float* __restrict__ dw_w,
    const float* __restrict__ dw_b, const float* __restrict__ bproj,
    const float* __restrict__ pw_b, float* __restrict__ out) {
  __shared__ unsigned short t_lds[8 * 14 * 128];  // [yl*14+xh][c], 256B rows, swz
  __shared__ unsigned short A_lds[64 * 64];       // [pix][k], 128B rows, swz
  __shared__ unsigned short B_lds[128 * 64];      // [o][k],   128B rows, swz
  char* t_c = (char*)t_lds; char* A_c = (char*)A_lds; char* B_c = (char*)B_lds;
  const int tid = threadIdx.x;
  // XCD-contiguous remap: each XCD gets 512 consecutive tiles (halo L2 reuse)
  const int bid0 = blockIdx.x;
  const int bid = (bid0 & 7) * 512 + (bid0 >> 3);
  const int b = bid >> 10;
  const int tile = bid & 1023;
  const int y0 = (tile >> 5) * 8;
  const int x0 = (tile & 31) * 8;

  // separable gabor weights from dw_w: a[i]=w[0][i][4], b_s[j]=w[s][4][j]
  float a_[7];
  #pragma unroll
  for (int i = 0; i < 7; ++i) a_[i] = dw_w[i * 7 + 4];
  float bco[4][7];
  #pragma unroll
  for (int s = 0; s < 4; ++s)
    #pragma unroll
    for (int j = 0; j < 7; ++j) bco[s][j] = dw_w[s * 49 + 28 + j];

  // ---- vertical 7-tap pass: t[yl][xh][c], xh covers x0-3..x0+10 ----
  #pragma unroll
  for (int it = 0; it < 2; ++it) {
    int colid = tid + 256 * it;
    if (colid < 448) {                 // 14 xh * 32 c-quads
      int xh = colid >> 5;
      int c4 = (colid & 31) * 4;
      int xg = x0 + xh - 3;
      bool inx = (xg >= 0) && (xg < 256);
      float rows_[14][4];
      #pragma unroll
      for (int yy = 0; yy < 14; ++yy) {
        int yg = y0 + yy - 3;
        float f0 = 0.f, f1 = 0.f, f2 = 0.f, f3 = 0.f;
        if (inx && yg >= 0 && yg < 256) {
          ushort4 vv = *(const ushort4*)&v[((long)b * 65536 + yg * 256 + xg) * 128 + c4];
          f0 = bf2f(vv.x); f1 = bf2f(vv.y); f2 = bf2f(vv.z); f3 = bf2f(vv.w);
        }
        rows_[yy][0] = f0; rows_[yy][1] = f1; rows_[yy][2] = f2; rows_[yy][3] = f3;
      }
      #pragma unroll
      for (int yl = 0; yl < 8; ++yl) {
        float t0 = 0.f, t1 = 0.f, t2 = 0.f, t3 = 0.f;
        #pragma unroll
        for (int i = 0; i < 7; ++i) {
          float w = a_[i];
          t0 += w * rows_[yl + i][0];
          t1 += w * rows_[yl + i][1];
          t2 += w * rows_[yl + i][2];
          t3 += w * rows_[yl + i][3];
        }
        ushort4 p; p.x = f2bf(t0); p.y = f2bf(t1); p.z = f2bf(t2); p.w = f2bf(t3);
        int trow = yl * 14 + xh;
        *(ushort4*)(t_c + trow * 256 + ((2 * c4) ^ ((trow & 15) << 4))) = p;
      }
    }
  }
  __syncthreads();

  const int wave = tid >> 6, lane = tid & 63;
  const int quad = lane >> 4, l16 = lane & 15;
  const int swl = (l16 & 7) << 4;
  f32x4 acc[8];
  #pragma unroll
  for (int nt = 0; nt < 8; ++nt) acc[nt] = (f32x4){0.f, 0.f, 0.f, 0.f};

  // K = 640 in 10 chunks of 64: kc 0..1 = v@W2 (attention), kc 2..9 = gabor@pw
  for (int kc = 0; kc < 10; ++kc) {
    { // stage B chunk: BT[o][k]
      int o = tid >> 1;
      int k0 = (tid & 1) * 32;
      const unsigned short* src = (kc < 2)
          ? (W2T + ((long)b * 128 + o) * 128 + kc * 64 + k0)
          : (pwb + (long)o * 512 + (kc - 2) * 64 + k0);
      const int sw = (o & 7) << 4;
      #pragma unroll
      for (int u = 0; u < 32; u += 8)
        *(uint4*)(B_c + o * 128 + ((2 * (k0 + u)) ^ sw)) = *(const uint4*)(src + u);
    }
    if (kc < 2) { // A chunk = v tile
      int pix = tid >> 2;
      int c0 = (tid & 3) * 16;
      const unsigned short* src =
          v + ((long)b * 65536 + (y0 + (pix >> 3)) * 256 + x0 + (pix & 7)) * 128 + kc * 64 + c0;
      const int sw = (pix & 7) << 4;
      *(uint4*)(A_c + pix * 128 + ((2 * c0) ^ sw))      = *(const uint4*)(src);
      *(uint4*)(A_c + pix * 128 + ((2 * c0 + 16) ^ sw)) = *(const uint4*)(src + 8);
    } else {      // A chunk = GELU(horizontal 7-tap of t) for c in [16kcg,16kcg+16)
      int kcg = kc - 2;
      int pix = tid >> 2;
      int cl = (tid & 3) * 4;
      int yl = pix >> 3, xl = pix & 7;
      float tv[7][4];
      #pragma unroll
      for (int j = 0; j < 7; ++j) {
        int trow = yl * 14 + xl + j;
        ushort4 tt = *(const ushort4*)(t_c + trow * 256 +
                                       ((32 * kcg + 2 * cl) ^ ((trow & 15) << 4)));
        tv[j][0] = bf2f(tt.x); tv[j][1] = bf2f(tt.y); tv[j][2] = bf2f(tt.z); tv[j][3] = bf2f(tt.w);
      }
      const int sw = (pix & 7) << 4;
      #pragma unroll
      for (int cc = 0; cc < 4; ++cc) {
        int ch = (16 * kcg + cl + cc) * 4;    // g-channel base = 4*c
        unsigned short gs[4];
        #pragma unroll
        for (int s = 0; s < 4; ++s) {
          float g = dw_b[ch + s];
          #pragma unroll
          for (int j = 0; j < 7; ++j) g += bco[s][j] * tv[j][cc];
          gs[s] = f2bf(gelu_f(g));
        }
        ushort4 p; p.x = gs[0]; p.y = gs[1]; p.z = gs[2]; p.w = gs[3];
        *(ushort4*)(A_c + pix * 128 + ((8 * (cl + cc)) ^ sw)) = p;  // k-local = 4*c_local+s
      }
    }
    __syncthreads();
    #pragma unroll
    for (int ks = 0; ks < 2; ++ks) {
      bf16x8 af = *(const bf16x8*)(A_c + (16 * wave + l16) * 128 +
                                   ((64 * ks + 16 * quad) ^ swl));
      #pragma unroll
      for (int nt = 0; nt < 8; ++nt) {
        bf16x8 bfr = *(const bf16x8*)(B_c + (16 * nt + l16) * 128 +
                                      ((64 * ks + 16 * quad) ^ swl));
        acc[nt] = __builtin_amdgcn_mfma_f32_16x16x32_bf16(af, bfr, acc[nt], 0, 0, 0);
      }
    }
    __syncthreads();
  }

  // epilogue: + bproj + pw_b, fp32 store
  int mr = 16 * wave + 4 * quad;
  #pragma unroll
  for (int nt = 0; nt < 8; ++nt) {
    int col = 16 * nt + l16;
    float bias = bproj[col] + pw_b[col];
    #pragma unroll
    for (int r = 0; r < 4; ++r) {
      int pix = mr + r;
      out[((long)b * 65536 + (y0 + (pix >> 3)) * 256 + x0 + (pix & 7)) * 128 + col] =
          acc[nt][r] + bias;
    }
  }
}

extern "C" void kernel_launch(void* const* d_in, const int* in_sizes, int n_in,
                              void* d_out, int out_size, void* d_ws, size_t ws_size,
                              hipStream_t stream) {
  const float* x       = (const float*)d_in[0];
  const float* Wq      = (const float*)d_in[1];
  const float* Wk      = (const float*)d_in[2];
  const float* Wv      = (const float*)d_in[3];
  const float* rescale = (const float*)d_in[4];
  const float* Wproj   = (const float*)d_in[5];
  const float* bproj   = (const float*)d_in[6];
  const float* dw_w    = (const float*)d_in[7];
  const float* dw_b    = (const float*)d_in[8];
  const float* pw_w    = (const float*)d_in[9];
  const float* pw_b    = (const float*)d_in[10];
  float* out = (float*)d_out;

  char* ws = (char*)d_ws;
  unsigned short* v       = (unsigned short*)(ws);
  float*          partial = (float*)(ws + 67108864);
  float*          S       = (float*)(ws + 100663296);
  unsigned short* W2T     = (unsigned short*)(ws + 100925440);
  unsigned short* pwb     = (unsigned short*)(ws + 101056512);

  k_prep  <<<512, 256, 0, stream>>>(pw_w, pwb, S);
  k_vgram <<<512, 256, 0, stream>>>(x, Wv, v, partial);
  k_reduce<<<1024,256, 0, stream>>>(partial, S);
  k_attn  <<<16,  256, 0, stream>>>(S, Wq, Wk, rescale, Wproj, W2T);
  k_final <<<4096,256, 0, stream>>>(v, W2T, pwb, dw_w, dw_b, bproj, pw_b, out);
}